// Round 2
// 251.244 us; speedup vs baseline: 1.1172x; 1.1172x over previous
//
#include <hip/hip_runtime.h>

// TTLinear fused: out = x @ (core0 @ core1)^T + bias, exploiting rank-8 structure.
// Single kernel; each block owns 8 tokens end-to-end:
//   Phase A: y[8][8] = x[8 tokens] @ core1^T  (reads 128 KB of x, y -> LDS)
//   Phase B: out[8][4096] = y @ core0^T + bias (writes 128 KB of out)
// Fusion overlaps the read stream (x) and write stream (out) across blocks,
// removes the y HBM round-trip, the second launch, and all d_ws usage.
// Nontemporal hints: x is read-once, out is write-once -> don't evict
// core1 (128 KB) / core0 (128 KB) from L2.

#define TOKENS 8192
#define IN_F   4096
#define OUT_F  4096
#define RANK   8
#define TB     8   // tokens per block (4 waves x 2 tokens)

// clang native vector type: required by __builtin_nontemporal_load/store
// (HIP_vector_type float4 is rejected). Same codegen: global_*_dwordx4 nt.
typedef float f32x4 __attribute__((ext_vector_type(4)));

__global__ __launch_bounds__(256) void tt_fused(const float* __restrict__ x,
                                                const float* __restrict__ core0,
                                                const float* __restrict__ core1,
                                                const float* __restrict__ bias,
                                                float* __restrict__ out) {
    __shared__ __align__(16) float y_lds[TB][RANK];   // 256 B

    const int tid  = threadIdx.x;
    const int wave = tid >> 6;
    const int lane = tid & 63;
    const int tblk = blockIdx.x * TB;
    const int t0   = tblk + wave * 2;

    // ---- Phase A: per wave, 2 tokens; lane l reads float4 at i = 4*(l+64k),
    // fully coalesced 1 KB/instr. core1 float4 reused across the wave's 2
    // tokens; core1 (128 KB) stays L2-resident thanks to nt-hints on x.
    const float* x0 = x + (size_t)t0 * IN_F;
    const float* x1 = x0 + IN_F;

    float acc0[RANK], acc1[RANK];
    #pragma unroll
    for (int r = 0; r < RANK; ++r) { acc0[r] = 0.f; acc1[r] = 0.f; }

    #pragma unroll 4
    for (int k = 0; k < 16; ++k) {
        const int i = 4 * (lane + 64 * k);
        const f32x4 a0 = __builtin_nontemporal_load((const f32x4*)(x0 + i));
        const f32x4 a1 = __builtin_nontemporal_load((const f32x4*)(x1 + i));
        #pragma unroll
        for (int r = 0; r < RANK; ++r) {
            const f32x4 c = *(const f32x4*)(core1 + r * IN_F + i);
            acc0[r] += a0.x * c.x + a0.y * c.y + a0.z * c.z + a0.w * c.w;
            acc1[r] += a1.x * c.x + a1.y * c.y + a1.z * c.z + a1.w * c.w;
        }
    }

    // butterfly reduce across the 64-lane wave
    #pragma unroll
    for (int r = 0; r < RANK; ++r) {
        #pragma unroll
        for (int off = 32; off > 0; off >>= 1) {
            acc0[r] += __shfl_xor(acc0[r], off, 64);
            acc1[r] += __shfl_xor(acc1[r], off, 64);
        }
    }

    if (lane == 0) {
        f32x4* yp0 = (f32x4*)&y_lds[wave * 2 + 0][0];
        f32x4* yp1 = (f32x4*)&y_lds[wave * 2 + 1][0];
        yp0[0] = (f32x4){acc0[0], acc0[1], acc0[2], acc0[3]};
        yp0[1] = (f32x4){acc0[4], acc0[5], acc0[6], acc0[7]};
        yp1[0] = (f32x4){acc1[0], acc1[1], acc1[2], acc1[3]};
        yp1[1] = (f32x4){acc1[4], acc1[5], acc1[6], acc1[7]};
    }
    __syncthreads();

    // ---- Phase B: thread owns 4 consecutive o's per o-group (float4 store),
    // 4 o-groups x 8 tokens. y reads are block-uniform LDS broadcasts.
    // og loop deliberately NOT unrolled: keeps w[8] live-range to one group
    // (32 VGPRs) instead of hoisting 128.
    #pragma unroll 1
    for (int og = 0; og < 4; ++og) {
        const int o = og * 1024 + tid * 4;
        f32x4 w[8];
        #pragma unroll
        for (int j = 0; j < 4; ++j) {
            w[2 * j]     = *(const f32x4*)(core0 + (o + j) * RANK);
            w[2 * j + 1] = *(const f32x4*)(core0 + (o + j) * RANK + 4);
        }
        const f32x4 b = *(const f32x4*)(bias + o);

        #pragma unroll
        for (int t = 0; t < TB; ++t) {
            const f32x4 y0 = *(const f32x4*)(&y_lds[t][0]);
            const f32x4 y1 = *(const f32x4*)(&y_lds[t][4]);
            f32x4 c;
            c.x = b.x + y0.x * w[0].x + y0.y * w[0].y + y0.z * w[0].z + y0.w * w[0].w
                      + y1.x * w[1].x + y1.y * w[1].y + y1.z * w[1].z + y1.w * w[1].w;
            c.y = b.y + y0.x * w[2].x + y0.y * w[2].y + y0.z * w[2].z + y0.w * w[2].w
                      + y1.x * w[3].x + y1.y * w[3].y + y1.z * w[3].z + y1.w * w[3].w;
            c.z = b.z + y0.x * w[4].x + y0.y * w[4].y + y0.z * w[4].z + y0.w * w[4].w
                      + y1.x * w[5].x + y1.y * w[5].y + y1.z * w[5].z + y1.w * w[5].w;
            c.w = b.w + y0.x * w[6].x + y0.y * w[6].y + y0.z * w[6].z + y0.w * w[6].w
                      + y1.x * w[7].x + y1.y * w[7].y + y1.z * w[7].z + y1.w * w[7].w;
            __builtin_nontemporal_store(c, (f32x4*)(out + (size_t)(tblk + t) * OUT_F + o));
        }
    }
}

extern "C" void kernel_launch(void* const* d_in, const int* in_sizes, int n_in,
                              void* d_out, int out_size, void* d_ws, size_t ws_size,
                              hipStream_t stream) {
    const float* x     = (const float*)d_in[0];  // [8192, 4096]
    const float* core0 = (const float*)d_in[1];  // [1, 4096, 8] -> [o][r]
    const float* core1 = (const float*)d_in[2];  // [8, 4096, 1] -> [r][i]
    const float* bias  = (const float*)d_in[3];  // [4096]
    float* out = (float*)d_out;                  // [8192, 4096]
    (void)d_ws; (void)ws_size;                   // workspace no longer used

    tt_fused<<<TOKENS / TB, 256, 0, stream>>>(x, core0, core1, bias, out);
}

// Round 3
// 248.226 us; speedup vs baseline: 1.1308x; 1.0122x over previous
//
#include <hip/hip_runtime.h>

// TTLinear fused: out = x @ (core0 @ core1)^T + bias, rank-8 structure.
// One kernel; each block owns 8 tokens end-to-end.
//   Phase A: y[8][8] = x[8 tokens] @ core1^T   (reads 128 KB of x)
//   Phase B: out[8][4096] = y @ core0^T + bias (writes 128 KB of out)
//
// R2->R3 change: each wave now covers 4 tokens x half of IN_F (was 2 tokens
// x all of IN_F). Wave pair (tg, ih=0/1) splits the i-range; partial sums
// combine through LDS. Effect: core1 L2 traffic halves (512->256 MB total),
// per-thread VMEM instrs 160->96, x-reuse per core1 load doubles. Same
// grid (1024 blocks), same occupancy (16 waves/CU), same HBM traffic.
// A/B intent: null delta => kernel is at the 256 MB HBM floor (~38us) and
// the remaining dur_us is harness poison-fill overhead.

#define TOKENS 8192
#define IN_F   4096
#define OUT_F  4096
#define RANK   8
#define TB     8   // tokens per block

// clang native vector type: required by __builtin_nontemporal_load/store
typedef float f32x4 __attribute__((ext_vector_type(4)));

__global__ __launch_bounds__(256) void tt_fused(const float* __restrict__ x,
                                                const float* __restrict__ core0,
                                                const float* __restrict__ core1,
                                                const float* __restrict__ bias,
                                                float* __restrict__ out) {
    // partial y per wave: [wave][token-in-group][rank] = 512 B
    __shared__ __align__(16) float y_part[4][4][RANK];

    const int tid   = threadIdx.x;
    const int wave  = tid >> 6;
    const int lane  = tid & 63;
    const int tblk  = blockIdx.x * TB;
    const int tg    = wave >> 1;          // token group: waves {0,1}->tokens 0-3, {2,3}->4-7
    const int ih    = wave & 1;           // i-half: 0 -> [0,2048), 1 -> [2048,4096)
    const int ibase = ih * (IN_F / 2);

    const float* xb = x + (size_t)(tblk + tg * 4) * IN_F + ibase;
    const float* cb = core1 + ibase;

    // ---- Phase A: 4 tokens, 2048-wide i-slice. Lane l reads float4 at
    // i = 4*(l + 64k), k = 0..7 -> fully coalesced 1 KB/instr on x.
    // Each core1 float4 feeds 4 tokens (was 2).
    float acc[4][RANK];
    #pragma unroll
    for (int t = 0; t < 4; ++t)
        #pragma unroll
        for (int r = 0; r < RANK; ++r) acc[t][r] = 0.f;

    #pragma unroll 4
    for (int k = 0; k < 8; ++k) {
        const int i = 4 * (lane + 64 * k);
        f32x4 a[4];
        #pragma unroll
        for (int t = 0; t < 4; ++t)
            a[t] = __builtin_nontemporal_load((const f32x4*)(xb + (size_t)t * IN_F + i));
        #pragma unroll
        for (int r = 0; r < RANK; ++r) {
            const f32x4 c = *(const f32x4*)(cb + r * IN_F + i);
            #pragma unroll
            for (int t = 0; t < 4; ++t)
                acc[t][r] += a[t].x * c.x + a[t].y * c.y + a[t].z * c.z + a[t].w * c.w;
        }
    }

    // butterfly reduce across the 64-lane wave (partial over this i-half)
    #pragma unroll
    for (int t = 0; t < 4; ++t)
        #pragma unroll
        for (int r = 0; r < RANK; ++r)
            #pragma unroll
            for (int off = 32; off > 0; off >>= 1)
                acc[t][r] += __shfl_xor(acc[t][r], off, 64);

    if (lane == 0) {
        #pragma unroll
        for (int t = 0; t < 4; ++t) {
            f32x4* yp = (f32x4*)&y_part[wave][t][0];
            yp[0] = (f32x4){acc[t][0], acc[t][1], acc[t][2], acc[t][3]};
            yp[1] = (f32x4){acc[t][4], acc[t][5], acc[t][6], acc[t][7]};
        }
    }
    __syncthreads();

    // ---- Phase B: thread owns 4 consecutive o's per o-group (float4 store),
    // 4 o-groups x 8 tokens. y = sum of the two i-half partials; LDS reads
    // are block-uniform broadcasts. og loop NOT unrolled (w[8] live-range).
    #pragma unroll 1
    for (int og = 0; og < 4; ++og) {
        const int o = og * 1024 + tid * 4;
        f32x4 w[8];
        #pragma unroll
        for (int j = 0; j < 4; ++j) {
            w[2 * j]     = *(const f32x4*)(core0 + (o + j) * RANK);
            w[2 * j + 1] = *(const f32x4*)(core0 + (o + j) * RANK + 4);
        }
        const f32x4 b = *(const f32x4*)(bias + o);

        #pragma unroll
        for (int t = 0; t < TB; ++t) {
            const int g  = t >> 2;   // token group
            const int tl = t & 3;    // token within group
            const f32x4 y0 = *(const f32x4*)&y_part[2 * g][tl][0]
                           + *(const f32x4*)&y_part[2 * g + 1][tl][0];
            const f32x4 y1 = *(const f32x4*)&y_part[2 * g][tl][4]
                           + *(const f32x4*)&y_part[2 * g + 1][tl][4];
            f32x4 c;
            c.x = b.x + y0.x * w[0].x + y0.y * w[0].y + y0.z * w[0].z + y0.w * w[0].w
                      + y1.x * w[1].x + y1.y * w[1].y + y1.z * w[1].z + y1.w * w[1].w;
            c.y = b.y + y0.x * w[2].x + y0.y * w[2].y + y0.z * w[2].z + y0.w * w[2].w
                      + y1.x * w[3].x + y1.y * w[3].y + y1.z * w[3].z + y1.w * w[3].w;
            c.z = b.z + y0.x * w[4].x + y0.y * w[4].y + y0.z * w[4].z + y0.w * w[4].w
                      + y1.x * w[5].x + y1.y * w[5].y + y1.z * w[5].z + y1.w * w[5].w;
            c.w = b.w + y0.x * w[6].x + y0.y * w[6].y + y0.z * w[6].z + y0.w * w[6].w
                      + y1.x * w[7].x + y1.y * w[7].y + y1.z * w[7].z + y1.w * w[7].w;
            __builtin_nontemporal_store(c, (f32x4*)(out + (size_t)(tblk + t) * OUT_F + o));
        }
    }
}

extern "C" void kernel_launch(void* const* d_in, const int* in_sizes, int n_in,
                              void* d_out, int out_size, void* d_ws, size_t ws_size,
                              hipStream_t stream) {
    const float* x     = (const float*)d_in[0];  // [8192, 4096]
    const float* core0 = (const float*)d_in[1];  // [1, 4096, 8] -> [o][r]
    const float* core1 = (const float*)d_in[2];  // [8, 4096, 1] -> [r][i]
    const float* bias  = (const float*)d_in[3];  // [4096]
    float* out = (float*)d_out;                  // [8192, 4096]
    (void)d_ws; (void)ws_size;                   // workspace not used

    tt_fused<<<TOKENS / TB, 256, 0, stream>>>(x, core0, core1, bias, out);
}